// Round 1
// baseline (240.799 us; speedup 1.0000x reference)
//
#include <hip/hip_runtime.h>
#include <math.h>

#define BB 8
#define NN 2048
#define DD 128
#define HH 8

typedef _Float16 v4h __attribute__((ext_vector_type(4)));
typedef float    v4f __attribute__((ext_vector_type(4)));

__device__ __forceinline__ v4f zero4() { v4f z = {0.f, 0.f, 0.f, 0.f}; return z; }

__device__ __forceinline__ v4f mfma16(v4h a, v4h b, v4f c) {
    return __builtin_amdgcn_mfma_f32_16x16x16f16(a, b, c, 0, 0, 0);
}

// LOGIT_SCALE = log(400)/log(50)/sqrt(16) = 0.38288787
#define CZ 0.76577574f   /* 2*LOGIT_SCALE */

// ---------------- prep: weights fp32->fp16, RoPE/xpos tables (double precision) ----------------
__global__ __launch_bounds__(256) void prep_kernel(
    const float* __restrict__ Wq, const float* __restrict__ Wk,
    const float* __restrict__ Wv, const float* __restrict__ Wo,
    _Float16* __restrict__ WH, _Float16* __restrict__ WoH,
    float* __restrict__ rtab)
{
    int tid = blockIdx.x * 256 + threadIdx.x;        // 65536 threads
    int m = tid >> 14, i = tid & 16383;
    const float* src = (m == 0) ? Wq : (m == 1) ? Wk : (m == 2) ? Wv : Wo;
    float wv = src[i];
    if (m < 3) WH[m * 16384 + i] = (_Float16)wv;
    else       WoH[i] = (_Float16)wv;

    if (tid < NN * 16) {
        int t = tid >> 4, hd = tid & 15, j = hd >> 1;
        float invf = (float)pow(10000.0, -(double)j / 8.0);
        float freq = (float)t * invf;                 // fp32 like reference
        double c = cos((double)freq), s = sin((double)freq);
        float scf = ((float)(2 * j) + 6.4f) / 22.4f;
        float pw  = ((float)t - 1024.0f) / 512.0f;
        double scl = pow((double)scf, (double)pw);
        rtab[0 * NN * 16 + tid] = (float)(c * scl);   // Q cos*scale
        rtab[1 * NN * 16 + tid] = (float)(s * scl);   // Q sin*scale
        rtab[2 * NN * 16 + tid] = (float)(c / scl);   // K cos/scale
        rtab[3 * NN * 16 + tid] = (float)(s / scl);   // K sin/scale
    }
}

// ---------------- fused QKV projection + RoPE ----------------
// Q,K: D = W*x^T (swapped operands -> channel index in regs, in-lane rotate-half, 8B stores)
// V:   D = x*W^T (token index in regs -> contiguous V^T stores)
__global__ __launch_bounds__(256) void proj_rope_kernel(
    const float* __restrict__ q, const float* __restrict__ k, const float* __restrict__ v,
    const _Float16* __restrict__ WH, const float* __restrict__ rtab,
    _Float16* __restrict__ Qr, _Float16* __restrict__ Kr, _Float16* __restrict__ VT)
{
    __shared__ __align__(16) _Float16 xb[3][64][136];   // 52 KB, padded stride (bank-safe)
    const int tid = threadIdx.x;
    const int r0 = blockIdx.x * 64;          // 64 token rows per block
    const int b  = r0 >> 11;
    const int n0 = r0 & 2047;

    const float* srcs[3] = {q, k, v};
    for (int m = 0; m < 3; ++m) {
        const float* s = srcs[m] + (size_t)r0 * 128;
        #pragma unroll
        for (int i = 0; i < 8; ++i) {
            int u = tid + i * 256;                       // 2048 float4 chunks
            int row = u >> 5, c4 = (u & 31) * 4;
            v4f f = *(const v4f*)(s + row * 128 + c4);
            v4h hv; hv[0]=(_Float16)f[0]; hv[1]=(_Float16)f[1]; hv[2]=(_Float16)f[2]; hv[3]=(_Float16)f[3];
            *(v4h*)&xb[m][row][c4] = hv;
        }
    }
    __syncthreads();

    const int w = tid >> 6, lane = tid & 63;
    const int l16 = lane & 15, quad = lane >> 4;

    for (int m = 0; m < 3; ++m) {
        v4h xf[8];
        #pragma unroll
        for (int kt = 0; kt < 8; ++kt)
            xf[kt] = *(const v4h*)&xb[m][w * 16 + l16][kt * 16 + quad * 4];
        const _Float16* Wm = WH + m * 16384;
        v4f acc[8];
        #pragma unroll
        for (int ct = 0; ct < 8; ++ct) acc[ct] = zero4();
        #pragma unroll
        for (int kt = 0; kt < 8; ++kt) {
            #pragma unroll
            for (int ct = 0; ct < 8; ++ct) {
                v4h wf = *(const v4h*)(Wm + (ct * 16 + l16) * 128 + kt * 16 + quad * 4);
                if (m < 2) acc[ct] = mfma16(wf, xf[kt], acc[ct]);   // D = W * x^T
                else       acc[ct] = mfma16(xf[kt], wf, acc[ct]);   // D = x * W^T
            }
        }
        if (m < 2) {
            // lane: token n = n0+w*16+l16 ; channel = ct*16 + quad*4 + r  (h=ct, hd=quad*4+r)
            const float* tc = rtab + (m == 0 ? 0 : 2 * NN * 16);
            const float* ts = tc + NN * 16;
            const int n = n0 + w * 16 + l16;
            _Float16* dst = (m == 0 ? Qr : Kr);
            #pragma unroll
            for (int ct = 0; ct < 8; ++ct) {
                v4f cs = *(const v4f*)(tc + n * 16 + quad * 4);
                v4f sn = *(const v4f*)(ts + n * 16 + quad * 4);
                v4f a = acc[ct];
                v4f rot; rot[0] = -a[1]; rot[1] = a[0]; rot[2] = -a[3]; rot[3] = a[2];
                v4h o;
                #pragma unroll
                for (int r = 0; r < 4; ++r) o[r] = (_Float16)(a[r] * cs[r] + rot[r] * sn[r]);
                *(v4h*)(dst + ((size_t)(b * 8 + ct) * NN + n) * 16 + quad * 4) = o;
            }
        } else {
            // lane: token = n0+w*16+quad*4+r ; h=ct, hd=l16 ; V^T layout (bh,16,N)
            #pragma unroll
            for (int ct = 0; ct < 8; ++ct) {
                v4f a = acc[ct];
                v4h o;
                #pragma unroll
                for (int r = 0; r < 4; ++r) o[r] = (_Float16)a[r];
                *(v4h*)(VT + ((size_t)(b * 8 + ct) * 16 + l16) * NN + n0 + w * 16 + quad * 4) = o;
            }
        }
    }
}

// ---------------- fused attention: S^T=K·Q^T -> exp(10·tanh) -> O^T += V^T·P^T ----------------
// No max-subtraction needed: logits bounded to ±10 by tanh clip.
__global__ __launch_bounds__(256) void attn_kernel(
    const _Float16* __restrict__ Qr, const _Float16* __restrict__ Kr,
    const _Float16* __restrict__ VT, const unsigned char* __restrict__ mask,
    _Float16* __restrict__ Obuf)
{
    __shared__ __align__(16) _Float16 Kt[64][20];    // padded: conflict-free A-frag reads
    __shared__ __align__(16) _Float16 VTt[16][68];
    __shared__ __align__(16) float    mf[64];

    const int tid = threadIdx.x;
    const int bh = blockIdx.x >> 5;                  // 64 (b,h) pairs
    const int qt = blockIdx.x & 31;                  // 32 q-tiles of 64
    const int b = bh >> 3, h = bh & 7;
    const int q0 = qt * 64;
    const int w = tid >> 6, lane = tid & 63;
    const int l16 = lane & 15, quad = lane >> 4;

    const int qrow = q0 + w * 16 + l16;
    v4h qf = *(const v4h*)(Qr + ((size_t)bh * NN + qrow) * 16 + quad * 4);  // Q[q=l16][d=quad*4+j]

    v4f ot = zero4();
    float psum = 0.f;

    const int srow = tid >> 2, sc4 = (tid & 3) * 4;
    const int vhd = tid >> 4, vn4 = (tid & 15) * 4;

    for (int k0 = 0; k0 < NN; k0 += 64) {
        __syncthreads();
        *(v4h*)&Kt[srow][sc4]  = *(const v4h*)(Kr + ((size_t)bh * NN + k0 + srow) * 16 + sc4);
        *(v4h*)&VTt[vhd][vn4]  = *(const v4h*)(VT + ((size_t)bh * 16 + vhd) * NN + k0 + vn4);
        if (tid < 64) mf[tid] = mask[b * NN + k0 + tid] ? 0.f : 1.f;
        __syncthreads();

        #pragma unroll
        for (int st = 0; st < 4; ++st) {
            v4h kf = *(const v4h*)&Kt[st * 16 + l16][quad * 4];
            v4f s  = mfma16(kf, qf, zero4());        // S^T[k=quad*4+r][q=l16]
            v4f mv = *(const v4f*)&mf[st * 16 + quad * 4];
            v4h ph;
            #pragma unroll
            for (int r = 0; r < 4; ++r) {
                // p = exp(10*tanh(z)) = exp(10 - 20/(e^{2z}+1)),  z = s*LOGIT_SCALE
                float u  = __expf(s[r] * CZ);
                float rc = __builtin_amdgcn_rcpf(u + 1.f);   // inf-safe: u=inf -> rc=0
                float p  = __expf(10.f - 20.f * rc) * mv[r];
                psum += p;
                ph[r] = (_Float16)p;                  // <= e^10 = 22026, fits fp16
            }
            v4h vf = *(const v4h*)&VTt[l16][st * 16 + quad * 4];
            ot = mfma16(vf, ph, ot);                  // O^T[vd=quad*4+r][q=l16]
        }
    }
    // denom: sum partial psum (per lane covers k%16 in quad*4..+3) across quads
    psum += __shfl_xor(psum, 16, 64);
    psum += __shfl_xor(psum, 32, 64);
    float rd = 1.0f / psum;
    v4h o;
    #pragma unroll
    for (int r = 0; r < 4; ++r) o[r] = (_Float16)(ot[r] * rd);
    *(v4h*)(Obuf + ((size_t)(b * NN + qrow) * 128) + h * 16 + quad * 4) = o;
}

// ---------------- output projection: out = O @ Wout^T (fp32 out) ----------------
__global__ __launch_bounds__(256) void outproj_kernel(
    const _Float16* __restrict__ Obuf, const _Float16* __restrict__ WoH,
    float* __restrict__ out)
{
    __shared__ __align__(16) _Float16 ob[64][136];
    const int tid = threadIdx.x;
    const int r0 = blockIdx.x * 64;
    #pragma unroll
    for (int i = 0; i < 8; ++i) {
        int u = tid + i * 256;
        int row = u >> 5, c4 = (u & 31) * 4;
        *(v4h*)&ob[row][c4] = *(const v4h*)(Obuf + (size_t)(r0 + row) * 128 + c4);
    }
    __syncthreads();
    const int w = tid >> 6, lane = tid & 63;
    const int l16 = lane & 15, quad = lane >> 4;
    v4h af[8];
    #pragma unroll
    for (int kt = 0; kt < 8; ++kt)
        af[kt] = *(const v4h*)&ob[w * 16 + l16][kt * 16 + quad * 4];
    v4f acc[8];
    #pragma unroll
    for (int ct = 0; ct < 8; ++ct) acc[ct] = zero4();
    #pragma unroll
    for (int kt = 0; kt < 8; ++kt)
        #pragma unroll
        for (int ct = 0; ct < 8; ++ct) {
            v4h wf = *(const v4h*)(WoH + (ct * 16 + l16) * 128 + kt * 16 + quad * 4);
            acc[ct] = mfma16(af[kt], wf, acc[ct]);
        }
    #pragma unroll
    for (int ct = 0; ct < 8; ++ct)
        #pragma unroll
        for (int r = 0; r < 4; ++r)
            out[(size_t)(r0 + w * 16 + quad * 4 + r) * 128 + ct * 16 + l16] = acc[ct][r];
}

extern "C" void kernel_launch(void* const* d_in, const int* in_sizes, int n_in,
                              void* d_out, int out_size, void* d_ws, size_t ws_size,
                              hipStream_t stream)
{
    const float* q  = (const float*)d_in[0];
    const float* k  = (const float*)d_in[1];
    const float* v  = (const float*)d_in[2];
    const float* Wq = (const float*)d_in[3];
    const float* Wk = (const float*)d_in[4];
    const float* Wv = (const float*)d_in[5];
    const float* Wo = (const float*)d_in[6];
    const unsigned char* mask = (const unsigned char*)d_in[7];
    float* out = (float*)d_out;

    char* ws = (char*)d_ws;
    _Float16* WH   = (_Float16*)(ws);                 //  96 KB  (Wq,Wk,Wv fp16)
    _Float16* WoH  = (_Float16*)(ws + 98304);         //  32 KB
    float*    rtab = (float*)(ws + 131072);           // 512 KB  (4 rope tables)
    _Float16* Qr   = (_Float16*)(ws + 655360);        //   4 MB  (B,H,N,16)
    _Float16* Kr   = (_Float16*)(ws + 4849664);       //   4 MB
    _Float16* VTd  = (_Float16*)(ws + 9043968);       //   4 MB  (B,H,16,N)
    _Float16* Obuf = (_Float16*)(ws + 13238272);      //   4 MB  (B*N,128)

    prep_kernel<<<256, 256, 0, stream>>>(Wq, Wk, Wv, Wo, WH, WoH, rtab);
    proj_rope_kernel<<<256, 256, 0, stream>>>(q, k, v, WH, rtab, Qr, Kr, VTd);
    attn_kernel<<<2048, 256, 0, stream>>>(Qr, Kr, VTd, mask, Obuf);
    outproj_kernel<<<256, 256, 0, stream>>>(Obuf, WoH, out);
}

// Round 2
// 211.062 us; speedup vs baseline: 1.1409x; 1.1409x over previous
//
#include <hip/hip_runtime.h>
#include <math.h>

#define BB 8
#define NN 2048
#define DD 128
#define HH 8

typedef _Float16 v4h __attribute__((ext_vector_type(4)));
typedef float    v4f __attribute__((ext_vector_type(4)));

__device__ __forceinline__ v4f zero4() { v4f z = {0.f, 0.f, 0.f, 0.f}; return z; }

__device__ __forceinline__ v4f mfma16(v4h a, v4h b, v4f c) {
    return __builtin_amdgcn_mfma_f32_16x16x16f16(a, b, c, 0, 0, 0);
}

__device__ __forceinline__ float fexp2(float x) {
#if __has_builtin(__builtin_amdgcn_exp2f)
    return __builtin_amdgcn_exp2f(x);          // v_exp_f32 (2^x)
#else
    return __expf(x * 0.69314718055994531f);
#endif
}

// LOGIT_SCALE = ln400/ln50/4 = 0.38288787333
// QSCALE = 2*LOGIT_SCALE*log2(e): folded into Q rope tables so S = log2(e^{2z})
#define QSCALE 1.10478088f
#define C1F 14.426950408889634f   /* 10*log2e */
#define C2F 28.853900817779268f   /* 20*log2e */

// ---------------- prep: weights fp32->fp16, RoPE/xpos tables (all fp32) ----------------
__global__ __launch_bounds__(256) void prep_kernel(
    const float* __restrict__ Wq, const float* __restrict__ Wk,
    const float* __restrict__ Wv, const float* __restrict__ Wo,
    _Float16* __restrict__ WH, _Float16* __restrict__ WoH,
    float* __restrict__ rtab)
{
    int tid = blockIdx.x * 256 + threadIdx.x;        // 65536 threads
    int m = tid >> 14, i = tid & 16383;
    const float* src = (m == 0) ? Wq : (m == 1) ? Wk : (m == 2) ? Wv : Wo;
    float wv = src[i];
    if (m < 3) WH[m * 16384 + i] = (_Float16)wv;
    else       WoH[i] = (_Float16)wv;

    if (tid < NN * 16) {
        int t = tid >> 4, hd = tid & 15, j = hd >> 1;
        // invf = 10000^(-j/8) = 10^(-j/2): exact constants (j=0 case, largest freq, is exact)
        const float invf_tab[8] = {1.f, 0.31622776601683794f, 0.1f, 0.031622776601683791f,
                                   0.01f, 0.0031622776601683794f, 0.001f, 0.00031622776601683794f};
        float freq = (float)t * invf_tab[j];
        float c = cosf(freq), s = sinf(freq);    // fp32, accurate arg reduction
        float scf = ((float)(2 * j) + 6.4f) / 22.4f;
        float pw  = ((float)t - 1024.0f) / 512.0f;
        float scl = exp2f(pw * log2f(scf));
        rtab[0 * NN * 16 + tid] = c * scl * QSCALE;   // Q cos*scale (pre-scaled)
        rtab[1 * NN * 16 + tid] = s * scl * QSCALE;   // Q sin*scale (pre-scaled)
        float is = 1.0f / scl;
        rtab[2 * NN * 16 + tid] = c * is;             // K cos/scale
        rtab[3 * NN * 16 + tid] = s * is;             // K sin/scale
    }
}

// ---------------- fused QKV projection + RoPE (one m per blockIdx.y) ----------------
// Q,K: D = W*x^T (channel index in regs -> in-lane rotate-half, 8B stores)
// V:   D = x*W^T (token index in regs -> contiguous V^T stores)
__global__ __launch_bounds__(256) void proj_rope_kernel(
    const float* __restrict__ q, const float* __restrict__ k, const float* __restrict__ v,
    const _Float16* __restrict__ WH, const float* __restrict__ rtab,
    _Float16* __restrict__ Qr, _Float16* __restrict__ Kr, _Float16* __restrict__ VT)
{
    __shared__ __align__(16) _Float16 xb[64][136];
    const int tid = threadIdx.x;
    const int m  = blockIdx.y;
    const int r0 = blockIdx.x * 64;          // 64 token rows per block
    const int b  = r0 >> 11;
    const int n0 = r0 & 2047;

    const float* s = ((m == 0) ? q : (m == 1) ? k : v) + (size_t)r0 * 128;
    #pragma unroll
    for (int i = 0; i < 8; ++i) {
        int u = tid + i * 256;                       // 2048 float4 chunks
        int row = u >> 5, c4 = (u & 31) * 4;
        v4f f = *(const v4f*)(s + row * 128 + c4);
        v4h hv; hv[0]=(_Float16)f[0]; hv[1]=(_Float16)f[1]; hv[2]=(_Float16)f[2]; hv[3]=(_Float16)f[3];
        *(v4h*)&xb[row][c4] = hv;
    }
    __syncthreads();

    const int w = tid >> 6, lane = tid & 63;
    const int l16 = lane & 15, quad = lane >> 4;

    v4h xf[8];
    #pragma unroll
    for (int kt = 0; kt < 8; ++kt)
        xf[kt] = *(const v4h*)&xb[w * 16 + l16][kt * 16 + quad * 4];
    const _Float16* Wm = WH + m * 16384;
    v4f acc[8];
    #pragma unroll
    for (int ct = 0; ct < 8; ++ct) acc[ct] = zero4();
    #pragma unroll
    for (int kt = 0; kt < 8; ++kt) {
        #pragma unroll
        for (int ct = 0; ct < 8; ++ct) {
            v4h wf = *(const v4h*)(Wm + (ct * 16 + l16) * 128 + kt * 16 + quad * 4);
            if (m < 2) acc[ct] = mfma16(wf, xf[kt], acc[ct]);   // D = W * x^T
            else       acc[ct] = mfma16(xf[kt], wf, acc[ct]);   // D = x * W^T
        }
    }
    if (m < 2) {
        // lane: token n = n0+w*16+l16 ; channel = ct*16 + quad*4 + r  (h=ct, hd=quad*4+r)
        const float* tc = rtab + (m == 0 ? 0 : 2 * NN * 16);
        const float* ts = tc + NN * 16;
        const int n = n0 + w * 16 + l16;
        _Float16* dst = (m == 0 ? Qr : Kr);
        #pragma unroll
        for (int ct = 0; ct < 8; ++ct) {
            v4f cs = *(const v4f*)(tc + n * 16 + quad * 4);
            v4f sn = *(const v4f*)(ts + n * 16 + quad * 4);
            v4f a = acc[ct];
            v4f rot; rot[0] = -a[1]; rot[1] = a[0]; rot[2] = -a[3]; rot[3] = a[2];
            v4h o;
            #pragma unroll
            for (int r = 0; r < 4; ++r) o[r] = (_Float16)(a[r] * cs[r] + rot[r] * sn[r]);
            *(v4h*)(dst + ((size_t)(b * 8 + ct) * NN + n) * 16 + quad * 4) = o;
        }
    } else {
        // lane: token = n0+w*16+quad*4+r ; h=ct, hd=l16 ; V^T layout (bh,16,N)
        #pragma unroll
        for (int ct = 0; ct < 8; ++ct) {
            v4f a = acc[ct];
            v4h o;
            #pragma unroll
            for (int r = 0; r < 4; ++r) o[r] = (_Float16)a[r];
            *(v4h*)(VT + ((size_t)(b * 8 + ct) * 16 + l16) * NN + n0 + w * 16 + quad * 4) = o;
        }
    }
}

// ---------------- fused attention ----------------
// S^T = K·Q^T (Q pre-scaled so u = 2^S = e^{2z}) -> p = e^{10tanh} = 2^(C1 - C2/(u+1))
// mask folded into the fma addend; row-sum via ones-MFMA in the idle MFMA pipe.
__global__ __launch_bounds__(256) void attn_kernel(
    const _Float16* __restrict__ Qr, const _Float16* __restrict__ Kr,
    const _Float16* __restrict__ VT, const unsigned char* __restrict__ mask,
    _Float16* __restrict__ Obuf)
{
    __shared__ __align__(16) _Float16 Kt[64][20];
    __shared__ __align__(16) _Float16 VTt[16][72];
    __shared__ __align__(16) float    av[64];

    const int tid = threadIdx.x;
    const int bh = blockIdx.x >> 4;                  // 64 (b,h) pairs
    const int qt = blockIdx.x & 15;                  // 16 q-tiles of 128
    const int b = bh >> 3, h = bh & 7;
    const int q0 = qt * 128;
    const int w = tid >> 6, lane = tid & 63;
    const int l16 = lane & 15, quad = lane >> 4;

    v4h qf[2];
    #pragma unroll
    for (int g = 0; g < 2; ++g) {
        int qrow = q0 + w * 32 + g * 16 + l16;
        qf[g] = *(const v4h*)(Qr + ((size_t)bh * NN + qrow) * 16 + quad * 4);
    }
    v4f ot[2]; ot[0] = zero4(); ot[1] = zero4();
    v4f sa[2]; sa[0] = zero4(); sa[1] = zero4();
    v4h ones; ones[0] = ones[1] = ones[2] = ones[3] = (_Float16)1.f;

    const int srow = tid >> 2, sc4 = (tid & 3) * 4;
    const int vhd = tid >> 4, vn4 = (tid & 15) * 4;

    for (int k0 = 0; k0 < NN; k0 += 64) {
        __syncthreads();
        *(v4h*)&Kt[srow][sc4]  = *(const v4h*)(Kr + ((size_t)bh * NN + k0 + srow) * 16 + sc4);
        *(v4h*)&VTt[vhd][vn4]  = *(const v4h*)(VT + ((size_t)bh * 16 + vhd) * NN + k0 + vn4);
        if (tid < 64) av[tid] = mask[b * NN + k0 + tid] ? -1e30f : C1F;
        __syncthreads();

        #pragma unroll
        for (int st = 0; st < 4; ++st) {
            v4h kf = *(const v4h*)&Kt[st * 16 + l16][quad * 4];
            v4f ad = *(const v4f*)&av[st * 16 + quad * 4];
            v4h vf = *(const v4h*)&VTt[l16][st * 16 + quad * 4];
            #pragma unroll
            for (int g = 0; g < 2; ++g) {
                v4f sv = mfma16(kf, qf[g], zero4());     // S^T[k=quad*4+r][q=l16]
                v4h ph;
                #pragma unroll
                for (int r = 0; r < 4; ++r) {
                    float u  = fexp2(sv[r]);                         // e^{2z}
                    float rc = __builtin_amdgcn_rcpf(u + 1.f);       // inf-safe
                    float p  = fexp2(__builtin_fmaf(rc, -C2F, ad[r]));
                    ph[r] = (_Float16)p;                              // <= e^10, fits fp16
                }
                ot[g] = mfma16(vf, ph, ot[g]);           // O^T[hd][q] accumulate
                sa[g] = mfma16(ones, ph, sa[g]);         // row sums (all regs equal)
            }
        }
    }
    #pragma unroll
    for (int g = 0; g < 2; ++g) {
        float rd = 1.0f / sa[g][0];
        v4h o;
        #pragma unroll
        for (int r = 0; r < 4; ++r) o[r] = (_Float16)(ot[g][r] * rd);
        int qrow = q0 + w * 32 + g * 16 + l16;
        *(v4h*)(Obuf + ((size_t)(b * NN + qrow) * 128) + h * 16 + quad * 4) = o;
    }
}

// ---------------- output projection: out = O @ Wout^T (fp32 out), col-split grid.y ----------------
__global__ __launch_bounds__(256) void outproj_kernel(
    const _Float16* __restrict__ Obuf, const _Float16* __restrict__ WoH,
    float* __restrict__ out)
{
    __shared__ __align__(16) _Float16 ob[64][136];
    const int tid = threadIdx.x;
    const int r0 = blockIdx.x * 64;
    const int ct0 = blockIdx.y * 4;
    #pragma unroll
    for (int i = 0; i < 8; ++i) {
        int u = tid + i * 256;
        int row = u >> 5, c4 = (u & 31) * 4;
        *(v4h*)&ob[row][c4] = *(const v4h*)(Obuf + (size_t)(r0 + row) * 128 + c4);
    }
    __syncthreads();
    const int w = tid >> 6, lane = tid & 63;
    const int l16 = lane & 15, quad = lane >> 4;
    v4h af[8];
    #pragma unroll
    for (int kt = 0; kt < 8; ++kt)
        af[kt] = *(const v4h*)&ob[w * 16 + l16][kt * 16 + quad * 4];
    v4f acc[4];
    #pragma unroll
    for (int c = 0; c < 4; ++c) acc[c] = zero4();
    #pragma unroll
    for (int kt = 0; kt < 8; ++kt)
        #pragma unroll
        for (int c = 0; c < 4; ++c) {
            v4h wf = *(const v4h*)(WoH + ((ct0 + c) * 16 + l16) * 128 + kt * 16 + quad * 4);
            acc[c] = mfma16(af[kt], wf, acc[c]);
        }
    #pragma unroll
    for (int c = 0; c < 4; ++c)
        #pragma unroll
        for (int r = 0; r < 4; ++r)
            out[(size_t)(r0 + w * 16 + quad * 4 + r) * 128 + (ct0 + c) * 16 + l16] = acc[c][r];
}

extern "C" void kernel_launch(void* const* d_in, const int* in_sizes, int n_in,
                              void* d_out, int out_size, void* d_ws, size_t ws_size,
                              hipStream_t stream)
{
    const float* q  = (const float*)d_in[0];
    const float* k  = (const float*)d_in[1];
    const float* v  = (const float*)d_in[2];
    const float* Wq = (const float*)d_in[3];
    const float* Wk = (const float*)d_in[4];
    const float* Wv = (const float*)d_in[5];
    const float* Wo = (const float*)d_in[6];
    const unsigned char* mask = (const unsigned char*)d_in[7];
    float* out = (float*)d_out;

    char* ws = (char*)d_ws;
    _Float16* WH   = (_Float16*)(ws);                 //  96 KB  (Wq,Wk,Wv fp16)
    _Float16* WoH  = (_Float16*)(ws + 98304);         //  32 KB
    float*    rtab = (float*)(ws + 131072);           // 512 KB  (4 rope tables)
    _Float16* Qr   = (_Float16*)(ws + 655360);        //   4 MB  (B,H,N,16)
    _Float16* Kr   = (_Float16*)(ws + 4849664);       //   4 MB
    _Float16* VTd  = (_Float16*)(ws + 9043968);       //   4 MB  (B,H,16,N)
    _Float16* Obuf = (_Float16*)(ws + 13238272);      //   4 MB  (B*N,128)

    prep_kernel<<<256, 256, 0, stream>>>(Wq, Wk, Wv, Wo, WH, WoH, rtab);
    proj_rope_kernel<<<dim3(256, 3), 256, 0, stream>>>(q, k, v, WH, rtab, Qr, Kr, VTd);
    attn_kernel<<<1024, 256, 0, stream>>>(Qr, Kr, VTd, mask, Obuf);
    outproj_kernel<<<dim3(256, 2), 256, 0, stream>>>(Obuf, WoH, out);
}